// Round 5
// baseline (399.579 us; speedup 1.0000x reference)
//
#include <hip/hip_runtime.h>

#define SEQ 8192
#define DIM 768

typedef __attribute__((ext_vector_type(8))) short s16x8;   // 8 x bf16
typedef __attribute__((ext_vector_type(4))) float f32x4;

// RNE float -> bf16
__device__ __forceinline__ unsigned short f2bf(float f) {
  union { float f; unsigned u; } v; v.f = f;
  unsigned r = v.u + 0x7FFFu + ((v.u >> 16) & 1u);
  return (unsigned short)(r >> 16);
}

__device__ __forceinline__ float bf2f(unsigned short s) {
  union { unsigned u; float f; } v; v.u = ((unsigned)s) << 16;
  return v.f;
}

// async global->LDS 16B copy: lds dest = wave-uniform base + lane*16
__device__ __forceinline__ void gll16(const void* gsrc, void* ldst) {
  __builtin_amdgcn_global_load_lds(
      (__attribute__((address_space(1))) unsigned int*)gsrc,
      (__attribute__((address_space(3))) unsigned int*)ldst, 16, 0, 0);
}

// ---------------- fused cast kernel: x (6144 blocks) + wq/wk/wv (576 each) ----------------
#define XN4 (SEQ * DIM / 4)     // 1572864
#define WN4 (DIM * DIM / 4)     // 147456

__global__ void cast_all_kernel(const float* __restrict__ x, const float* __restrict__ wq,
                                const float* __restrict__ wk, const float* __restrict__ wv,
                                unsigned short* __restrict__ dx, unsigned short* __restrict__ dq,
                                unsigned short* __restrict__ dk, unsigned short* __restrict__ dv) {
  int i = blockIdx.x * blockDim.x + threadIdx.x;
  const float* s;
  unsigned short* d;
  int off;
  if (i < XN4) {
    s = x; d = dx; off = i;
  } else {
    int j = i - XN4;
    int wi = j / WN4;
    off = j - wi * WN4;
    s = (wi == 0) ? wq : ((wi == 1) ? wk : wv);
    d = (wi == 0) ? dq : ((wi == 1) ? dk : dv);
  }
  float4 v = ((const float4*)s)[off];
  ushort4 r; r.x = f2bf(v.x); r.y = f2bf(v.y); r.z = f2bf(v.z); r.w = f2bf(v.w);
  ((ushort4*)d)[off] = r;
}

// ---------------- projection GEMM: C[m][n] = sum_k X[m][k]*W[n][k] ----------------
// z==2 writes V in key-blocked layout: Vt_blk[key>>5][vr 768][key&31]
__global__ __launch_bounds__(256, 2)
void proj_kernel(const unsigned short* __restrict__ X,
                 const unsigned short* __restrict__ Wq,
                 const unsigned short* __restrict__ Wk,
                 const unsigned short* __restrict__ Wv,
                 unsigned short* __restrict__ Qb,
                 unsigned short* __restrict__ Kb,
                 unsigned short* __restrict__ Vtb) {
  __shared__ __align__(16) char lds[65536];
  const int tid = threadIdx.x;
  const int lane = tid & 63, wv = tid >> 6;
  const int l15 = lane & 15, l4 = lane >> 4;
  const int mt = blockIdx.x, nt = blockIdx.y, z = blockIdx.z;
  const unsigned short* W = (z == 0) ? Wq : ((z == 1) ? Wk : Wv);

  f32x4 acc[4][4];
#pragma unroll
  for (int i = 0; i < 4; ++i)
#pragma unroll
    for (int j = 0; j < 4; ++j) acc[i][j] = f32x4{0.f, 0.f, 0.f, 0.f};

  auto stage = [&](int kk) {
    char* At = lds + (kk & 1) * 32768;
    char* Bt = At + 16384;
    const int d0 = kk * 64;
#pragma unroll
    for (int i = 0; i < 4; ++i) {
      int s = i * 256 + tid;
      int row = s >> 3, c = (s & 7) ^ (row & 7);
      gll16(X + (long)(mt * 128 + row) * DIM + d0 + c * 8, At + i * 4096 + (wv << 10));
      gll16(W + (long)(nt * 128 + row) * DIM + d0 + c * 8, Bt + i * 4096 + (wv << 10));
    }
  };

  stage(0);
#pragma unroll 1
  for (int kk = 0; kk < 12; ++kk) {
    __syncthreads();
    if (kk + 1 < 12) stage(kk + 1);
    const char* At = lds + (kk & 1) * 32768;
    const char* Bt = At + 16384;
#pragma unroll
    for (int ks = 0; ks < 2; ++ks) {
      const int c = ks * 4 + l4;
      s16x8 a[4], b[4];
#pragma unroll
      for (int mi = 0; mi < 4; ++mi) {
        int row = (wv & 1) * 64 + mi * 16 + l15;
        a[mi] = *(const s16x8*)(At + row * 128 + ((c ^ (row & 7)) << 4));
      }
#pragma unroll
      for (int ni = 0; ni < 4; ++ni) {
        int row = (wv >> 1) * 64 + ni * 16 + l15;
        b[ni] = *(const s16x8*)(Bt + row * 128 + ((c ^ (row & 7)) << 4));
      }
#pragma unroll
      for (int mi = 0; mi < 4; ++mi)
#pragma unroll
        for (int ni = 0; ni < 4; ++ni)
          acc[mi][ni] = __builtin_amdgcn_mfma_f32_16x16x32_bf16(a[mi], b[ni], acc[mi][ni], 0, 0, 0);
    }
  }

#pragma unroll
  for (int mi = 0; mi < 4; ++mi)
#pragma unroll
    for (int ni = 0; ni < 4; ++ni) {
      int row0 = mt * 128 + (wv & 1) * 64 + mi * 16 + l4 * 4;
      int col = nt * 128 + (wv >> 1) * 64 + ni * 16 + l15;
      if (z == 2) {
        ushort4 r;
        r.x = f2bf(acc[mi][ni][0]); r.y = f2bf(acc[mi][ni][1]);
        r.z = f2bf(acc[mi][ni][2]); r.w = f2bf(acc[mi][ni][3]);
        // blocked: [row0>>5][col][row0&31]; keys row0..row0+3 stay in one 32-block
        *(ushort4*)(Vtb + (long)(row0 >> 5) * (DIM * 32) + col * 32 + (row0 & 31)) = r;
      } else {
        unsigned short* dst = (z == 0) ? Qb : Kb;
#pragma unroll
        for (int g = 0; g < 4; ++g)
          dst[(long)(row0 + g) * DIM + col] = f2bf(acc[mi][ni][g]);
      }
    }
}

// ---------------- flash attention: 80KB-LDS variant for 2 blocks/CU ----------------
// BM=64 q rows/block, BN=256 keys/iter, 8 waves, all 16x16x32 MFMA.
// LDS (81920 B): two 24KB slots S0=[0,24576) S1=[24576,49152); P=[49152,81920).
//   QK round r (32 dims; 24 rounds): buf r&1; Qc 4KB @ +0, Kc 16KB @ +4096.
//   PV chunk v (32 keys x 384 d; 16 chunks): slot v&1, 24KB = [384 vr][32 keys],
//     64B rows, swizzle slot = c ^ ((row>>1)&3) (2-way-free reads, linear stage).
//   pa fragments persist in regs across the two d-halves of each key-block.
// Slot audit: QK r reads buf r&1, stages buf (r+1)&1; r=23 (reads buf1) stages
//   V chunk0 -> S0; PV v reads slot v&1, stages slot (v+1)&1; v=15 (reads S1)
//   stages next-iter QK(0) -> buf0 c S0. Every dest last read >=1 barrier ago.
// l_part aliases lds[0..1024) post-loop.
#define SCALE_LOG2E 0.05205878f  // (1/sqrt(768)) * log2(e)

__global__ __launch_bounds__(512, 2)
void flash_kernel(const unsigned short* __restrict__ Q,   // [8192][768] bf16
                  const unsigned short* __restrict__ K,   // [8192][768] bf16
                  const unsigned short* __restrict__ V,   // blocked Vt [256][768][32] bf16
                  unsigned short* __restrict__ partp,     // [G][8192][768] bf16 (G-split mode)
                  float* __restrict__ outf,               // [8192][768] fp32 (norm mode)
                  float* __restrict__ lout,               // [G][8192] (G-split mode)
                  int kv_len, int norm_out) {
  __shared__ __align__(16) char lds[81920];
  char* Pl = lds + 49152;
  float* l_part = (float*)lds;  // [4][64], used only after the main loop

  const int tid = threadIdx.x;
  const int lane = tid & 63, wv = tid >> 6;
  const int l15 = lane & 15, l4 = lane >> 4;
  const int qtile = blockIdx.x, split = blockIdx.y;
  const long kv0 = (long)split * kv_len;
  const long qrow0 = (long)qtile * 64;
  const int R = wv & 1;   // S row-half
  const int C = wv >> 1;  // S key-quarter

  f32x4 acc_o[4][6];
  float acc_lp[8];
#pragma unroll
  for (int i = 0; i < 4; ++i)
#pragma unroll
    for (int j = 0; j < 6; ++j) acc_o[i][j] = f32x4{0.f, 0.f, 0.f, 0.f};
#pragma unroll
  for (int i = 0; i < 8; ++i) acc_lp[i] = 0.f;

  const int niter = kv_len >> 8;

  // QK stage: round r covers dims [r*32, r*32+32). Q 4KB (tid<256), K 16KB.
  auto stageQK = [&](int r, long kbase) {
    char* buf = lds + (r & 1) * 24576;
    char* Qc = buf;
    char* Kc = buf + 4096;
    const int d0 = r * 32;
    if (tid < 256) {
      int row = tid >> 2, p = tid & 3;
      int c = p ^ ((row >> 1) & 3);
      gll16(Q + (qrow0 + row) * DIM + d0 + c * 8, Qc + (wv << 10));
    }
#pragma unroll
    for (int i = 0; i < 2; ++i) {
      int s = i * 512 + tid;
      int row = s >> 2, p = s & 3;
      int c = p ^ ((row >> 1) & 3);
      gll16(K + (kbase + row) * DIM + d0 + c * 8, Kc + i * 8192 + (wv << 10));
    }
  };

  // PV stage: chunk v = key-block v>>1 (32 keys), d-half v&1 (384 vr). 24KB.
  auto stagePV = [&](int v, long kblk0) {
    char* Vc = lds + (v & 1) * 24576;
    const long blkbase = (kblk0 + (v >> 1)) * (long)(DIM * 32);
    const int dh = v & 1;
#pragma unroll
    for (int i = 0; i < 3; ++i) {
      int s = i * 512 + tid;
      int vr = s >> 2, p = s & 3;
      int c = p ^ ((vr >> 1) & 3);
      gll16(V + blkbase + (long)(dh * 384 + vr) * 32 + c * 8, Vc + i * 8192 + (wv << 10));
    }
  };

  stageQK(0, kv0);
#pragma unroll 1
  for (int it = 0; it < niter; ++it) {
    const long kb = kv0 + (long)it * 256;
    const long kblk0 = kb >> 5;

    // ---- QK: S[64x256], per-wave region [32 rows x 64 keys] = 2x4 16x16 tiles ----
    f32x4 acc_s[2][4];
#pragma unroll
    for (int a = 0; a < 2; ++a)
#pragma unroll
      for (int b = 0; b < 4; ++b) acc_s[a][b] = f32x4{0.f, 0.f, 0.f, 0.f};

#pragma unroll 1
    for (int r = 0; r < 24; ++r) {
      __syncthreads();  // drains stage(r); all waves done with prior compute
      if (r + 1 < 24) stageQK(r + 1, kb);
      else stagePV(0, kblk0);  // dest S0; r=23 reads buf1=S1 -> disjoint
      const char* buf = lds + (r & 1) * 24576;
      const char* Qc = buf;
      const char* Kc = buf + 4096;
      s16x8 af[2], bk[4];
#pragma unroll
      for (int rt = 0; rt < 2; ++rt) {
        int row = R * 32 + rt * 16 + l15;
        af[rt] = *(const s16x8*)(Qc + row * 64 + ((l4 ^ ((row >> 1) & 3)) << 4));
      }
#pragma unroll
      for (int ct = 0; ct < 4; ++ct) {
        int kr = C * 64 + ct * 16 + l15;
        bk[ct] = *(const s16x8*)(Kc + kr * 64 + ((l4 ^ ((kr >> 1) & 3)) << 4));
      }
#pragma unroll
      for (int rt = 0; rt < 2; ++rt)
#pragma unroll
        for (int ct = 0; ct < 4; ++ct)
          acc_s[rt][ct] = __builtin_amdgcn_mfma_f32_16x16x32_bf16(af[rt], bk[ct], acc_s[rt][ct], 0, 0, 0);
    }

    // ---- P = exp(S/sqrt(D)) -> bf16 -> LDS (swizzled [64][256]); per-lane l partials ----
#pragma unroll
    for (int rt = 0; rt < 2; ++rt)
#pragma unroll
      for (int ct = 0; ct < 4; ++ct)
#pragma unroll
        for (int g = 0; g < 4; ++g) {
          float p = exp2f(acc_s[rt][ct][g] * SCALE_LOG2E);
          acc_lp[rt * 4 + g] += p;
          int row = R * 32 + rt * 16 + l4 * 4 + g;
          int col = C * 64 + ct * 16 + l15;
          int off = row * 512 + ((((col >> 3) ^ (row & 7))) << 4) + ((col & 7) << 1);
          *(unsigned short*)(Pl + off) = f2bf(p);
        }

    // ---- PV: O[64x768] += P[64x256] @ V; 16 chunks (8 key-blocks x 2 d-halves) ----
    s16x8 pa[4];
#pragma unroll 2
    for (int v = 0; v < 16; ++v) {
      __syncthreads();  // drains stage(v) (+P ds_writes at v=0); prev readers done
      if (v + 1 < 16) stagePV(v + 1, kblk0);
      else if (it + 1 < niter) stageQK(0, kb + 256);  // dest buf0 c S0; v=15 reads S1
      const char* Vc = lds + (v & 1) * 24576;
      const int dh = v & 1;
      if (dh == 0) {  // new key-block: load pa, persist across both d-halves
        const int ck = (v >> 1) * 4 + l4;
#pragma unroll
        for (int rs = 0; rs < 4; ++rs) {
          int row = rs * 16 + l15;
          int pc = (ck & ~7) | ((ck & 7) ^ (row & 7));
          pa[rs] = *(const s16x8*)(Pl + row * 512 + (pc << 4));
        }
      }
#pragma unroll
      for (int j = 0; j < 3; ++j) {
        int vr = j * 128 + wv * 16 + l15;
        s16x8 vb = *(const s16x8*)(Vc + vr * 64 + ((l4 ^ ((vr >> 1) & 3)) << 4));
#pragma unroll
        for (int rs = 0; rs < 4; ++rs)
          acc_o[rs][dh * 3 + j] =
              __builtin_amdgcn_mfma_f32_16x16x32_bf16(pa[rs], vb, acc_o[rs][dh * 3 + j], 0, 0, 0);
      }
    }
  }

  // ---- l reduction: butterfly over lane bits 0..3 (16 cols/group), combine quarters ----
#pragma unroll
  for (int i = 0; i < 8; ++i) {
    float v = acc_lp[i];
    v += __shfl_xor(v, 1); v += __shfl_xor(v, 2);
    v += __shfl_xor(v, 4); v += __shfl_xor(v, 8);
    acc_lp[i] = v;
  }
  __syncthreads();  // all staging/reads done before l_part alias use
  if (l15 == 0) {
#pragma unroll
    for (int rt = 0; rt < 2; ++rt)
#pragma unroll
      for (int g = 0; g < 4; ++g)
        l_part[C * 64 + R * 32 + rt * 16 + l4 * 4 + g] = acc_lp[rt * 4 + g];
  }
  __syncthreads();

  if (!norm_out) {
    if (tid < 64)
      lout[(long)split * SEQ + qrow0 + tid] =
          l_part[tid] + l_part[64 + tid] + l_part[128 + tid] + l_part[192 + tid];
#pragma unroll
    for (int rt = 0; rt < 4; ++rt) {
      int row = rt * 16 + l4 * 4;
#pragma unroll
      for (int j = 0; j < 6; ++j) {
        int cc = j >> 1, t = j & 1;
        int col = (cc * 16 + wv + 8 * t) * 16 + l15;
#pragma unroll
        for (int g = 0; g < 4; ++g)
          partp[(long)split * SEQ * DIM + (qrow0 + row + g) * DIM + col] = f2bf(acc_o[rt][j][g]);
      }
    }
  } else {
    float linv[4][4];
#pragma unroll
    for (int rt = 0; rt < 4; ++rt)
#pragma unroll
      for (int g = 0; g < 4; ++g) {
        int row = rt * 16 + l4 * 4 + g;
        linv[rt][g] = 1.0f / (l_part[row] + l_part[64 + row] + l_part[128 + row] + l_part[192 + row]);
      }
#pragma unroll
    for (int rt = 0; rt < 4; ++rt) {
      int row = rt * 16 + l4 * 4;
#pragma unroll
      for (int j = 0; j < 6; ++j) {
        int cc = j >> 1, t = j & 1;
        int col = (cc * 16 + wv + 8 * t) * 16 + l15;
#pragma unroll
        for (int g = 0; g < 4; ++g)
          outf[(qrow0 + row + g) * DIM + col] = acc_o[rt][j][g] * linv[rt][g];
      }
    }
  }
}

// ---------------- combine (G splits): out = (sum p_g) / (sum l_g), partials bf16 ----------------
__global__ void combine_kernel(const unsigned short* __restrict__ part,
                               const float* __restrict__ lsum,
                               float* __restrict__ out, int n4, int nsplit) {
  int i = blockIdx.x * blockDim.x + threadIdx.x;
  if (i >= n4) return;
  int row = (i * 4) / DIM;
  float4 o = {0.f, 0.f, 0.f, 0.f};
  float l = 0.f;
#pragma unroll 4
  for (int g = 0; g < nsplit; ++g) {
    ushort4 p = ((const ushort4*)(part + (long)g * SEQ * DIM))[i];
    o.x += bf2f(p.x); o.y += bf2f(p.y); o.z += bf2f(p.z); o.w += bf2f(p.w);
    l += lsum[(long)g * SEQ + row];
  }
  float inv = 1.0f / l;
  o.x *= inv; o.y *= inv; o.z *= inv; o.w *= inv;
  ((float4*)out)[i] = o;
}

// ---------------- host ----------------
extern "C" void kernel_launch(void* const* d_in, const int* in_sizes, int n_in,
                              void* d_out, int out_size, void* d_ws, size_t ws_size,
                              hipStream_t stream) {
  const float* x = (const float*)d_in[0];
  const float* wq = (const float*)d_in[1];
  const float* wk = (const float*)d_in[2];
  const float* wv = (const float*)d_in[3];
  float* out = (float*)d_out;
  char* ws = (char*)d_ws;

  const size_t o_xbf = 0;
  const size_t o_wq = o_xbf + (size_t)SEQ * DIM * 2;
  const size_t o_wk = o_wq + (size_t)DIM * DIM * 2;
  const size_t o_wv = o_wk + (size_t)DIM * DIM * 2;
  const size_t o_q = o_wv + (size_t)DIM * DIM * 2;
  const size_t o_k = o_q + (size_t)SEQ * DIM * 2;
  const size_t o_vt = o_k + (size_t)SEQ * DIM * 2;
  const size_t o_part = o_vt + (size_t)SEQ * DIM * 2;
  const size_t o_l4 = o_part + (size_t)4 * SEQ * DIM * 2;
  const size_t total_g4 = o_l4 + (size_t)4 * SEQ * 4;
  const size_t o_l2 = o_part + (size_t)2 * SEQ * DIM * 2;
  const size_t total_g2 = o_l2 + (size_t)2 * SEQ * 4;

  unsigned short* Xbf = (unsigned short*)(ws + o_xbf);
  unsigned short* Wqb = (unsigned short*)(ws + o_wq);
  unsigned short* Wkb = (unsigned short*)(ws + o_wk);
  unsigned short* Wvb = (unsigned short*)(ws + o_wv);
  unsigned short* Qb = (unsigned short*)(ws + o_q);
  unsigned short* Kb = (unsigned short*)(ws + o_k);
  unsigned short* Vtb = (unsigned short*)(ws + o_vt);
  unsigned short* part = (unsigned short*)(ws + o_part);

  int G;
  size_t o_l;
  if (ws_size >= total_g4) { G = 4; o_l = o_l4; }
  else if (ws_size >= total_g2) { G = 2; o_l = o_l2; }
  else { G = 1; o_l = o_part; }
  float* lbuf = (float*)(ws + o_l);

  cast_all_kernel<<<7872, 256, 0, stream>>>(x, wq, wk, wv, Xbf, Wqb, Wkb, Wvb);
  proj_kernel<<<dim3(64, 6, 3), 256, 0, stream>>>(Xbf, Wqb, Wkb, Wvb, Qb, Kb, Vtb);
  if (G > 1) {
    flash_kernel<<<dim3(128, G), 512, 0, stream>>>(Qb, Kb, Vtb, part, nullptr, lbuf, SEQ / G, 0);
    combine_kernel<<<6144, 256, 0, stream>>>(part, lbuf, out, SEQ * DIM / 4, G);
  } else {
    flash_kernel<<<dim3(128, 1), 512, 0, stream>>>(Qb, Kb, Vtb, nullptr, out, nullptr, SEQ, 1);
  }
}